// Round 1
// baseline (205.291 us; speedup 1.0000x reference)
//
#include <hip/hip_runtime.h>
#include <math.h>

#define BB 16
#define NPTS 16384
#define KK 32

// ---------------- Phase 1: per-(b,k) moment sums, chunked ----------------
// grid: (NCHUNK1, BB), block 256. thread: k = tid&31, plane = tid>>5.
#define CHUNK1 1024
#define NCHUNK1 (NPTS / CHUNK1)   // 16

__global__ __launch_bounds__(256) void phase1_kernel(
    const float* __restrict__ pc, const float* __restrict__ mask,
    const float* __restrict__ flow, float* __restrict__ p1) {
  const int b = blockIdx.y;
  const int chunk = blockIdx.x;
  const int tid = threadIdx.x;
  const int plane = tid >> 5;

  const float* pcb = pc + (size_t)b * NPTS * 3;
  const float* flb = flow + (size_t)b * NPTS * 3;
  const size_t mbase = ((size_t)b * NPTS + (size_t)chunk * CHUNK1) * KK;

  float w = 0.f;
  float ax = 0.f, ay = 0.f, az = 0.f;     // sum m*pc1
  float bx = 0.f, by = 0.f, bz = 0.f;     // sum m*pc2
  float M00 = 0.f, M01 = 0.f, M02 = 0.f;  // sum m*pc1_d*pc2_e
  float M10 = 0.f, M11 = 0.f, M12 = 0.f;
  float M20 = 0.f, M21 = 0.f, M22 = 0.f;

  const int base_p = chunk * CHUNK1 + plane;
#pragma unroll 4
  for (int i = 0; i < CHUNK1 / 8; ++i) {
    const int p = base_p + i * 8;
    const float m = mask[mbase + (size_t)i * 256 + tid];  // fully coalesced
    const float px = pcb[p * 3 + 0];
    const float py = pcb[p * 3 + 1];
    const float pz = pcb[p * 3 + 2];
    const float qx = px + flb[p * 3 + 0];
    const float qy = py + flb[p * 3 + 1];
    const float qz = pz + flb[p * 3 + 2];
    w += m;
    const float mx = m * px, my = m * py, mz = m * pz;
    ax += mx; ay += my; az += mz;
    bx = fmaf(m, qx, bx); by = fmaf(m, qy, by); bz = fmaf(m, qz, bz);
    M00 = fmaf(mx, qx, M00); M01 = fmaf(mx, qy, M01); M02 = fmaf(mx, qz, M02);
    M10 = fmaf(my, qx, M10); M11 = fmaf(my, qy, M11); M12 = fmaf(my, qz, M12);
    M20 = fmaf(mz, qx, M20); M21 = fmaf(mz, qy, M21); M22 = fmaf(mz, qz, M22);
  }

  __shared__ float red[256][17];  // +1 pad breaks bank conflicts
  red[tid][0] = w;
  red[tid][1] = ax; red[tid][2] = ay; red[tid][3] = az;
  red[tid][4] = bx; red[tid][5] = by; red[tid][6] = bz;
  red[tid][7] = M00; red[tid][8] = M01; red[tid][9] = M02;
  red[tid][10] = M10; red[tid][11] = M11; red[tid][12] = M12;
  red[tid][13] = M20; red[tid][14] = M21; red[tid][15] = M22;
  __syncthreads();

  if (tid < 32) {
    float s[16];
#pragma unroll
    for (int v = 0; v < 16; ++v) s[v] = 0.f;
#pragma unroll
    for (int pl = 0; pl < 8; ++pl) {
#pragma unroll
      for (int v = 0; v < 16; ++v) s[v] += red[pl * 32 + tid][v];
    }
    float* dst = p1 + (((size_t)b * NCHUNK1 + chunk) * 32 + tid) * 16;
#pragma unroll
    for (int v = 0; v < 16; ++v) dst[v] = s[v];
  }
}

// ---------------- Phase 2: 512 independent 3x3 Kabsch solves (fp64) -------
__global__ void phase2_kernel(const float* __restrict__ p1,
                              float* __restrict__ rt) {
  const int idx = blockIdx.x * blockDim.x + threadIdx.x;
  if (idx >= BB * KK) return;
  const int b = idx >> 5, k = idx & 31;

  double s[16];
#pragma unroll
  for (int v = 0; v < 16; ++v) s[v] = 0.0;
  for (int c = 0; c < NCHUNK1; ++c) {
    const float* src = p1 + (((size_t)b * NCHUNK1 + c) * 32 + k) * 16;
#pragma unroll
    for (int v = 0; v < 16; ++v) s[v] += (double)src[v];
  }

  const double w = s[0];
  const double mu1[3] = {s[1] / w, s[2] / w, s[3] / w};
  const double bs[3] = {s[4], s[5], s[6]};
  const double mu2[3] = {bs[0] / w, bs[1] / w, bs[2] / w};

  double S[3][3];
#pragma unroll
  for (int d = 0; d < 3; ++d)
#pragma unroll
    for (int e = 0; e < 3; ++e) S[d][e] = s[7 + d * 3 + e] - mu1[d] * bs[e];

  // A = S^T S (symmetric PSD)
  double A[3][3];
#pragma unroll
  for (int i = 0; i < 3; ++i)
#pragma unroll
    for (int j = 0; j < 3; ++j)
      A[i][j] = S[0][i] * S[0][j] + S[1][i] * S[1][j] + S[2][i] * S[2][j];

  double V[3][3] = {{1, 0, 0}, {0, 1, 0}, {0, 0, 1}};

  // cyclic Jacobi, 8 sweeps
  for (int sweep = 0; sweep < 8; ++sweep) {
#pragma unroll
    for (int pair = 0; pair < 3; ++pair) {
      const int p = (pair == 0) ? 0 : (pair == 1) ? 0 : 1;
      const int q = (pair == 0) ? 1 : (pair == 1) ? 2 : 2;
      const double apq = A[p][q];
      if (fabs(apq) < 1e-300) continue;
      const double app = A[p][p], aqq = A[q][q];
      const double tau = (aqq - app) / (2.0 * apq);
      const double tt =
          ((tau >= 0.0) ? 1.0 : -1.0) / (fabs(tau) + sqrt(1.0 + tau * tau));
      const double c = 1.0 / sqrt(1.0 + tt * tt);
      const double sn = tt * c;
      const int r = 3 - p - q;
      const double arp = A[r][p], arq = A[r][q];
      A[r][p] = A[p][r] = c * arp - sn * arq;
      A[r][q] = A[q][r] = sn * arp + c * arq;
      A[p][p] = app - tt * apq;
      A[q][q] = aqq + tt * apq;
      A[p][q] = A[q][p] = 0.0;
#pragma unroll
      for (int i = 0; i < 3; ++i) {
        const double vip = V[i][p], viq = V[i][q];
        V[i][p] = c * vip - sn * viq;
        V[i][q] = sn * vip + c * viq;
      }
    }
  }

  // sort eigenvalues descending
  int id0 = 0, id1 = 1, id2 = 2;
  double lam[3] = {A[0][0], A[1][1], A[2][2]};
  if (lam[id0] < lam[id1]) { int t = id0; id0 = id1; id1 = t; }
  if (lam[id0] < lam[id2]) { int t = id0; id0 = id2; id2 = t; }
  if (lam[id1] < lam[id2]) { int t = id1; id1 = id2; id2 = t; }
  const int ord[3] = {id0, id1, id2};

  double Vs[3][3], U[3][3];
#pragma unroll
  for (int j = 0; j < 3; ++j) {
    const int cj = ord[j];
    const double lj = lam[cj] > 0.0 ? lam[cj] : 0.0;
    const double sig = sqrt(lj);
    const double inv = 1.0 / (sig > 1e-30 ? sig : 1e-30);
#pragma unroll
    for (int i = 0; i < 3; ++i) Vs[i][j] = V[i][cj];
#pragma unroll
    for (int i = 0; i < 3; ++i)
      U[i][j] =
          (S[i][0] * Vs[0][j] + S[i][1] * Vs[1][j] + S[i][2] * Vs[2][j]) * inv;
  }

  const double detS = S[0][0] * (S[1][1] * S[2][2] - S[1][2] * S[2][1]) -
                      S[0][1] * (S[1][0] * S[2][2] - S[1][2] * S[2][0]) +
                      S[0][2] * (S[1][0] * S[2][1] - S[1][1] * S[2][0]);
  const double sgn = (detS >= 0.0) ? 1.0 : -1.0;

  double R[3][3];
#pragma unroll
  for (int i = 0; i < 3; ++i)
#pragma unroll
    for (int j = 0; j < 3; ++j)
      R[i][j] = Vs[i][0] * U[j][0] + Vs[i][1] * U[j][1] + sgn * Vs[i][2] * U[j][2];

  double tv[3];
#pragma unroll
  for (int i = 0; i < 3; ++i)
    tv[i] = mu2[i] - (R[i][0] * mu1[0] + R[i][1] * mu1[1] + R[i][2] * mu1[2]);

  float* dst = rt + (size_t)idx * 12;
#pragma unroll
  for (int i = 0; i < 3; ++i)
#pragma unroll
    for (int j = 0; j < 3; ++j) dst[i * 3 + j] = (float)R[i][j];
#pragma unroll
  for (int i = 0; i < 3; ++i) dst[9 + i] = (float)tv[i];
}

// ---------------- Phase 3: blend + per-point L2 norm, block partials ------
#define CHUNK3 1024
#define NCHUNK3 (NPTS / CHUNK3)  // 16

__global__ __launch_bounds__(256) void phase3_kernel(
    const float* __restrict__ pc, const float* __restrict__ mask,
    const float* __restrict__ flow, const float* __restrict__ rt,
    float* __restrict__ p3) {
  const int b = blockIdx.y;
  const int chunk = blockIdx.x;
  const int tid = threadIdx.x;
  const int k = tid & 31;
  const int plane = tid >> 5;

  const float* Rp = rt + (((size_t)b * KK) + k) * 12;
  const float R00 = Rp[0], R01 = Rp[1], R02 = Rp[2];
  const float R10 = Rp[3], R11 = Rp[4], R12 = Rp[5];
  const float R20 = Rp[6], R21 = Rp[7], R22 = Rp[8];
  const float t0 = Rp[9], t1 = Rp[10], t2 = Rp[11];

  const float* pcb = pc + (size_t)b * NPTS * 3;
  const float* flb = flow + (size_t)b * NPTS * 3;
  const size_t mbase = ((size_t)b * NPTS + (size_t)chunk * CHUNK3) * KK;

  float acc = 0.f;
  const int base_p = chunk * CHUNK3 + plane;
  for (int i = 0; i < CHUNK3 / 8; ++i) {
    const int p = base_p + i * 8;
    const float m = mask[mbase + (size_t)i * 256 + tid];  // coalesced
    const float px = pcb[p * 3 + 0];
    const float py = pcb[p * 3 + 1];
    const float pz = pcb[p * 3 + 2];
    float vx = m * fmaf(R00, px, fmaf(R01, py, fmaf(R02, pz, t0)));
    float vy = m * fmaf(R10, px, fmaf(R11, py, fmaf(R12, pz, t1)));
    float vz = m * fmaf(R20, px, fmaf(R21, py, fmaf(R22, pz, t2)));
    // butterfly-sum over the 32 k-lanes
#pragma unroll
    for (int off = 16; off >= 1; off >>= 1) {
      vx += __shfl_xor(vx, off, 32);
      vy += __shfl_xor(vy, off, 32);
      vz += __shfl_xor(vz, off, 32);
    }
    if (k == 0) {
      const float qx = px + flb[p * 3 + 0];
      const float qy = py + flb[p * 3 + 1];
      const float qz = pz + flb[p * 3 + 2];
      const float dx = vx - qx, dy = vy - qy, dz = vz - qz;
      acc += sqrtf(dx * dx + dy * dy + dz * dz);
    }
  }

  // block reduction
#pragma unroll
  for (int off = 32; off >= 1; off >>= 1) acc += __shfl_xor(acc, off, 64);
  __shared__ float sred[4];
  if ((tid & 63) == 0) sred[tid >> 6] = acc;
  __syncthreads();
  if (tid == 0)
    p3[(size_t)b * NCHUNK3 + chunk] = sred[0] + sred[1] + sred[2] + sred[3];
}

// ---------------- Phase 4: final deterministic reduce ---------------------
__global__ void phase4_kernel(const float* __restrict__ p3,
                              float* __restrict__ out) {
  const int tid = threadIdx.x;  // 256
  float v = p3[tid];
#pragma unroll
  for (int off = 32; off >= 1; off >>= 1) v += __shfl_xor(v, off, 64);
  __shared__ float sr[4];
  if ((tid & 63) == 0) sr[tid >> 6] = v;
  __syncthreads();
  if (tid == 0)
    out[0] = (sr[0] + sr[1] + sr[2] + sr[3]) * (1.0f / ((float)BB * NPTS));
}

extern "C" void kernel_launch(void* const* d_in, const int* in_sizes, int n_in,
                              void* d_out, int out_size, void* d_ws,
                              size_t ws_size, hipStream_t stream) {
  const float* pc = (const float*)d_in[0];
  const float* mask = (const float*)d_in[1];
  const float* flow = (const float*)d_in[2];
  float* out = (float*)d_out;
  float* ws = (float*)d_ws;

  // ws layout (floats): rt[512*12]=6144 | p1[256 blocks * 512]=131072 | p3[256]
  float* rt = ws;
  float* p1 = ws + 6144;
  float* p3 = ws + 6144 + (size_t)BB * NCHUNK1 * 32 * 16;

  phase1_kernel<<<dim3(NCHUNK1, BB), 256, 0, stream>>>(pc, mask, flow, p1);
  phase2_kernel<<<2, 256, 0, stream>>>(p1, rt);
  phase3_kernel<<<dim3(NCHUNK3, BB), 256, 0, stream>>>(pc, mask, flow, rt, p3);
  phase4_kernel<<<1, 256, 0, stream>>>(p3, out);
}

// Round 2
// 113.450 us; speedup vs baseline: 1.8095x; 1.8095x over previous
//
#include <hip/hip_runtime.h>
#include <math.h>

#define BB 16
#define NPTS 16384
#define KK 32

// ---------------- Phase 1: per-(b,k) moment sums, chunked ----------------
// grid: (NCHUNK1, BB), block 256. thread: k = tid&31, plane = tid>>5.
#define CHUNK1 512
#define NCHUNK1 (NPTS / CHUNK1)   // 32

__global__ __launch_bounds__(256) void phase1_kernel(
    const float* __restrict__ pc, const float* __restrict__ mask,
    const float* __restrict__ flow, float* __restrict__ p1) {
  const int b = blockIdx.y;
  const int chunk = blockIdx.x;
  const int tid = threadIdx.x;
  const int plane = tid >> 5;

  const float* pcb = pc + (size_t)b * NPTS * 3;
  const float* flb = flow + (size_t)b * NPTS * 3;
  const size_t mbase = ((size_t)b * NPTS + (size_t)chunk * CHUNK1) * KK;

  float w = 0.f;
  float ax = 0.f, ay = 0.f, az = 0.f;     // sum m*pc1
  float bx = 0.f, by = 0.f, bz = 0.f;     // sum m*pc2
  float M00 = 0.f, M01 = 0.f, M02 = 0.f;  // sum m*pc1_d*pc2_e
  float M10 = 0.f, M11 = 0.f, M12 = 0.f;
  float M20 = 0.f, M21 = 0.f, M22 = 0.f;

  const int base_p = chunk * CHUNK1 + plane;
#pragma unroll 4
  for (int i = 0; i < CHUNK1 / 8; ++i) {
    const int p = base_p + i * 8;
    const float m = mask[mbase + (size_t)i * 256 + tid];  // fully coalesced
    const float px = pcb[p * 3 + 0];
    const float py = pcb[p * 3 + 1];
    const float pz = pcb[p * 3 + 2];
    const float qx = px + flb[p * 3 + 0];
    const float qy = py + flb[p * 3 + 1];
    const float qz = pz + flb[p * 3 + 2];
    w += m;
    const float mx = m * px, my = m * py, mz = m * pz;
    ax += mx; ay += my; az += mz;
    bx = fmaf(m, qx, bx); by = fmaf(m, qy, by); bz = fmaf(m, qz, bz);
    M00 = fmaf(mx, qx, M00); M01 = fmaf(mx, qy, M01); M02 = fmaf(mx, qz, M02);
    M10 = fmaf(my, qx, M10); M11 = fmaf(my, qy, M11); M12 = fmaf(my, qz, M12);
    M20 = fmaf(mz, qx, M20); M21 = fmaf(mz, qy, M21); M22 = fmaf(mz, qz, M22);
  }

  __shared__ float red[256][17];  // +1 pad breaks bank conflicts
  red[tid][0] = w;
  red[tid][1] = ax; red[tid][2] = ay; red[tid][3] = az;
  red[tid][4] = bx; red[tid][5] = by; red[tid][6] = bz;
  red[tid][7] = M00; red[tid][8] = M01; red[tid][9] = M02;
  red[tid][10] = M10; red[tid][11] = M11; red[tid][12] = M12;
  red[tid][13] = M20; red[tid][14] = M21; red[tid][15] = M22;
  __syncthreads();

  if (tid < 32) {
    float s[16];
#pragma unroll
    for (int v = 0; v < 16; ++v) s[v] = 0.f;
#pragma unroll
    for (int pl = 0; pl < 8; ++pl) {
#pragma unroll
      for (int v = 0; v < 16; ++v) s[v] += red[pl * 32 + tid][v];
    }
    float* dst = p1 + (((size_t)b * NCHUNK1 + chunk) * 32 + tid) * 16;
#pragma unroll
    for (int v = 0; v < 16; ++v) dst[v] = s[v];
  }
}

// ---------------- Phase 2: 512 independent 3x3 Kabsch solves (fp64) -------
__global__ void phase2_kernel(const float* __restrict__ p1,
                              float* __restrict__ rt) {
  const int idx = blockIdx.x * blockDim.x + threadIdx.x;
  if (idx >= BB * KK) return;
  const int b = idx >> 5, k = idx & 31;

  double s[16];
#pragma unroll
  for (int v = 0; v < 16; ++v) s[v] = 0.0;
  for (int c = 0; c < NCHUNK1; ++c) {
    const float* src = p1 + (((size_t)b * NCHUNK1 + c) * 32 + k) * 16;
#pragma unroll
    for (int v = 0; v < 16; ++v) s[v] += (double)src[v];
  }

  const double w = s[0];
  const double mu1[3] = {s[1] / w, s[2] / w, s[3] / w};
  const double bs[3] = {s[4], s[5], s[6]};
  const double mu2[3] = {bs[0] / w, bs[1] / w, bs[2] / w};

  double S[3][3];
#pragma unroll
  for (int d = 0; d < 3; ++d)
#pragma unroll
    for (int e = 0; e < 3; ++e) S[d][e] = s[7 + d * 3 + e] - mu1[d] * bs[e];

  // A = S^T S (symmetric PSD)
  double A[3][3];
#pragma unroll
  for (int i = 0; i < 3; ++i)
#pragma unroll
    for (int j = 0; j < 3; ++j)
      A[i][j] = S[0][i] * S[0][j] + S[1][i] * S[1][j] + S[2][i] * S[2][j];

  double V[3][3] = {{1, 0, 0}, {0, 1, 0}, {0, 0, 1}};

  // cyclic Jacobi, 8 sweeps
  for (int sweep = 0; sweep < 8; ++sweep) {
#pragma unroll
    for (int pair = 0; pair < 3; ++pair) {
      const int p = (pair == 0) ? 0 : (pair == 1) ? 0 : 1;
      const int q = (pair == 0) ? 1 : (pair == 1) ? 2 : 2;
      const double apq = A[p][q];
      if (fabs(apq) < 1e-300) continue;
      const double app = A[p][p], aqq = A[q][q];
      const double tau = (aqq - app) / (2.0 * apq);
      const double tt =
          ((tau >= 0.0) ? 1.0 : -1.0) / (fabs(tau) + sqrt(1.0 + tau * tau));
      const double c = 1.0 / sqrt(1.0 + tt * tt);
      const double sn = tt * c;
      const int r = 3 - p - q;
      const double arp = A[r][p], arq = A[r][q];
      A[r][p] = A[p][r] = c * arp - sn * arq;
      A[r][q] = A[q][r] = sn * arp + c * arq;
      A[p][p] = app - tt * apq;
      A[q][q] = aqq + tt * apq;
      A[p][q] = A[q][p] = 0.0;
#pragma unroll
      for (int i = 0; i < 3; ++i) {
        const double vip = V[i][p], viq = V[i][q];
        V[i][p] = c * vip - sn * viq;
        V[i][q] = sn * vip + c * viq;
      }
    }
  }

  // sort eigenvalues descending
  int id0 = 0, id1 = 1, id2 = 2;
  double lam[3] = {A[0][0], A[1][1], A[2][2]};
  if (lam[id0] < lam[id1]) { int t = id0; id0 = id1; id1 = t; }
  if (lam[id0] < lam[id2]) { int t = id0; id0 = id2; id2 = t; }
  if (lam[id1] < lam[id2]) { int t = id1; id1 = id2; id2 = t; }
  const int ord[3] = {id0, id1, id2};

  double Vs[3][3], U[3][3];
#pragma unroll
  for (int j = 0; j < 3; ++j) {
    const int cj = ord[j];
    const double lj = lam[cj] > 0.0 ? lam[cj] : 0.0;
    const double sig = sqrt(lj);
    const double inv = 1.0 / (sig > 1e-30 ? sig : 1e-30);
#pragma unroll
    for (int i = 0; i < 3; ++i) Vs[i][j] = V[i][cj];
#pragma unroll
    for (int i = 0; i < 3; ++i)
      U[i][j] =
          (S[i][0] * Vs[0][j] + S[i][1] * Vs[1][j] + S[i][2] * Vs[2][j]) * inv;
  }

  const double detS = S[0][0] * (S[1][1] * S[2][2] - S[1][2] * S[2][1]) -
                      S[0][1] * (S[1][0] * S[2][2] - S[1][2] * S[2][0]) +
                      S[0][2] * (S[1][0] * S[2][1] - S[1][1] * S[2][0]);
  const double sgn = (detS >= 0.0) ? 1.0 : -1.0;

  double R[3][3];
#pragma unroll
  for (int i = 0; i < 3; ++i)
#pragma unroll
    for (int j = 0; j < 3; ++j)
      R[i][j] = Vs[i][0] * U[j][0] + Vs[i][1] * U[j][1] + sgn * Vs[i][2] * U[j][2];

  double tv[3];
#pragma unroll
  for (int i = 0; i < 3; ++i)
    tv[i] = mu2[i] - (R[i][0] * mu1[0] + R[i][1] * mu1[1] + R[i][2] * mu1[2]);

  float* dst = rt + (size_t)idx * 12;
#pragma unroll
  for (int i = 0; i < 3; ++i)
#pragma unroll
    for (int j = 0; j < 3; ++j) dst[i * 3 + j] = (float)R[i][j];
#pragma unroll
  for (int i = 0; i < 3; ++i) dst[9 + i] = (float)tv[i];
}

// ---------------- Phase 3: thread-per-point blend + L2 norm ---------------
// grid: (NCHUNK3, BB), block 256 = 256 points per block. No shuffles in the
// hot loop: C = sum_k m_k [R_k|t_k] accumulated from LDS-broadcast float4s.
#define PTS3 256
#define NCHUNK3 (NPTS / PTS3)  // 64

__global__ __launch_bounds__(256) void phase3_kernel(
    const float* __restrict__ pc, const float* __restrict__ mask,
    const float* __restrict__ flow, const float* __restrict__ rt,
    float* __restrict__ p3) {
  const int b = blockIdx.y;
  const int chunk = blockIdx.x;
  const int tid = threadIdx.x;

  __shared__ float4 sR[KK * 3];  // 32 x [R|t] as 3 float4 each
  for (int l = tid; l < KK * 3; l += 256)
    sR[l] = ((const float4*)rt)[(size_t)b * KK * 3 + l];
  __syncthreads();

  const int p = chunk * PTS3 + tid;
  const float4* mrow = (const float4*)(mask + ((size_t)b * NPTS + p) * KK);
  float4 mv[8];
#pragma unroll
  for (int j = 0; j < 8; ++j) mv[j] = mrow[j];

  const float* pcp = pc + ((size_t)b * NPTS + p) * 3;
  const float* flp = flow + ((size_t)b * NPTS + p) * 3;
  const float px = pcp[0], py = pcp[1], pz = pcp[2];

  float C[12];
#pragma unroll
  for (int v = 0; v < 12; ++v) C[v] = 0.f;

#pragma unroll
  for (int k = 0; k < KK; ++k) {
    const float m = ((const float*)&mv[k >> 2])[k & 3];
    const float4 r0 = sR[k * 3 + 0];  // R00 R01 R02 R10
    const float4 r1 = sR[k * 3 + 1];  // R11 R12 R20 R21
    const float4 r2 = sR[k * 3 + 2];  // R22 t0  t1  t2
    C[0] = fmaf(m, r0.x, C[0]); C[1] = fmaf(m, r0.y, C[1]);
    C[2] = fmaf(m, r0.z, C[2]); C[3] = fmaf(m, r0.w, C[3]);
    C[4] = fmaf(m, r1.x, C[4]); C[5] = fmaf(m, r1.y, C[5]);
    C[6] = fmaf(m, r1.z, C[6]); C[7] = fmaf(m, r1.w, C[7]);
    C[8] = fmaf(m, r2.x, C[8]); C[9] = fmaf(m, r2.y, C[9]);
    C[10] = fmaf(m, r2.z, C[10]); C[11] = fmaf(m, r2.w, C[11]);
  }

  const float vx = fmaf(C[0], px, fmaf(C[1], py, fmaf(C[2], pz, C[9])));
  const float vy = fmaf(C[3], px, fmaf(C[4], py, fmaf(C[5], pz, C[10])));
  const float vz = fmaf(C[6], px, fmaf(C[7], py, fmaf(C[8], pz, C[11])));

  const float qx = px + flp[0];
  const float qy = py + flp[1];
  const float qz = pz + flp[2];
  const float dx = vx - qx, dy = vy - qy, dz = vz - qz;
  float acc = sqrtf(dx * dx + dy * dy + dz * dz);

  // block reduction
#pragma unroll
  for (int off = 32; off >= 1; off >>= 1) acc += __shfl_xor(acc, off, 64);
  __shared__ float sred[4];
  if ((tid & 63) == 0) sred[tid >> 6] = acc;
  __syncthreads();
  if (tid == 0)
    p3[(size_t)b * NCHUNK3 + chunk] = sred[0] + sred[1] + sred[2] + sred[3];
}

// ---------------- Phase 4: final deterministic reduce ---------------------
__global__ void phase4_kernel(const float* __restrict__ p3,
                              float* __restrict__ out) {
  const int tid = threadIdx.x;  // 256, reduces BB*NCHUNK3 = 1024 partials
  float v = 0.f;
#pragma unroll
  for (int j = 0; j < 4; ++j) v += p3[j * 256 + tid];
#pragma unroll
  for (int off = 32; off >= 1; off >>= 1) v += __shfl_xor(v, off, 64);
  __shared__ float sr[4];
  if ((tid & 63) == 0) sr[tid >> 6] = v;
  __syncthreads();
  if (tid == 0)
    out[0] = (sr[0] + sr[1] + sr[2] + sr[3]) * (1.0f / ((float)BB * NPTS));
}

extern "C" void kernel_launch(void* const* d_in, const int* in_sizes, int n_in,
                              void* d_out, int out_size, void* d_ws,
                              size_t ws_size, hipStream_t stream) {
  const float* pc = (const float*)d_in[0];
  const float* mask = (const float*)d_in[1];
  const float* flow = (const float*)d_in[2];
  float* out = (float*)d_out;
  float* ws = (float*)d_ws;

  // ws layout (floats):
  //   rt [512*12 = 6144] | p1 [16*32*32*16 = 262144] | p3 [1024]
  float* rt = ws;
  float* p1 = ws + 6144;
  float* p3 = ws + 6144 + (size_t)BB * NCHUNK1 * 32 * 16;

  phase1_kernel<<<dim3(NCHUNK1, BB), 256, 0, stream>>>(pc, mask, flow, p1);
  phase2_kernel<<<2, 256, 0, stream>>>(p1, rt);
  phase3_kernel<<<dim3(NCHUNK3, BB), 256, 0, stream>>>(pc, mask, flow, rt, p3);
  phase4_kernel<<<1, 256, 0, stream>>>(p3, out);
}